// Round 5
// baseline (344.905 us; speedup 1.0000x reference)
//
#include <hip/hip_runtime.h>
#include <hip/hip_bf16.h>
#include <math.h>

// ---------------- problem constants ----------------
#define P_N   300
#define C_N   512
#define H_F   50
#define W_F   67
#define HW_F  3350
#define D_N   1024
#define FIN   25088
#define NCLS  21
#define NCAND 6000
#define W_IMG 1072.0f
#define H_IMG 800.0f
#define BBOX_CLIP_F 4.135166556742356f
#define KS6   42
#define STEPS6_PER_Z 19
#define KS7   16
#define STEPS7_PER_Z 2
#define KSH   16
#define STEPSH_PER_Z 2
#define NHEAD 128
#define NW    96            // suppression-mask words per row (96*64 = 6144 >= NCAND)
#define LO_SCALE 2048.0f
#define LO_INV   (1.0f/2048.0f)

typedef __attribute__((ext_vector_type(8)))  _Float16 half8;
typedef __attribute__((ext_vector_type(16))) float    f32x16;

__device__ __forceinline__ void split16(float f, _Float16& h, _Float16& l) {
  h = (_Float16)f;
  l = (_Float16)((f - (float)h) * LO_SCALE);
}

// ---------------- feat (C,H,W) -> (H*W, C) transpose ----------------
__global__ __launch_bounds__(256) void transpose_feat(const float* __restrict__ feat,
                                                      float* __restrict__ ft) {
  __shared__ float tile[32][33];
  const int s0 = blockIdx.x * 32, c0 = blockIdx.y * 32;
  const int tx = threadIdx.x, ty = threadIdx.y;
  for (int r = ty; r < 32; r += 8) {
    int c = c0 + r, s = s0 + tx;
    tile[r][tx] = (s < HW_F) ? feat[(size_t)c * HW_F + s] : 0.0f;
  }
  __syncthreads();
  for (int r = ty; r < 32; r += 8) {
    int s = s0 + r, c = c0 + tx;
    if (s < HW_F) ft[(size_t)s * C_N + c] = tile[tx][r];
  }
}

// ---------------- ROI align: block per (proposal, channel-half) ----------------
__global__ __launch_bounds__(256) void roi_align_k(const float* __restrict__ ft,
                                                   const float* __restrict__ rois,
                                                   _Float16* __restrict__ Xhi,
                                                   _Float16* __restrict__ Xlo) {
  __shared__ _Float16 hbuf[12544] __attribute__((aligned(16)));
  __shared__ _Float16 lbuf[12544] __attribute__((aligned(16)));
  __shared__ int   g_yl[14], g_yh[14], g_xl[14], g_xh[14];
  __shared__ float g_ly[14], g_hy[14], g_lx[14], g_hx[14];
  __shared__ int   g_vy[14], g_vx[14];

  const int p   = blockIdx.x;
  const int ch  = blockIdx.y;
  const int tid = threadIdx.x;

  if (tid < 14) {
    const float rx0 = rois[p*4+0], ry0 = rois[p*4+1], rx1 = rois[p*4+2], ry1 = rois[p*4+3];
    const float x0r = rx0 * 0.0625f - 0.5f;
    const float y0r = ry0 * 0.0625f - 0.5f;
    const float bw  = (rx1 - rx0) * 0.0625f * (1.0f / 7.0f);
    const float bh  = (ry1 - ry0) * 0.0625f * (1.0f / 7.0f);
    const float t   = ((float)tid + 0.5f) * 0.5f;

    const float ys = y0r + bh * t;
    g_vy[tid] = (ys >= -1.0f) && (ys <= (float)H_F);
    float y = fminf(fmaxf(ys, 0.0f), (float)(H_F - 1));
    int yi = (int)floorf(y);
    g_yl[tid] = yi; g_yh[tid] = min(yi + 1, H_F - 1);
    g_ly[tid] = y - (float)yi; g_hy[tid] = 1.0f - (y - (float)yi);

    const float xs = x0r + bw * t;
    g_vx[tid] = (xs >= -1.0f) && (xs <= (float)W_F);
    float x = fminf(fmaxf(xs, 0.0f), (float)(W_F - 1));
    int xi = (int)floorf(x);
    g_xl[tid] = xi; g_xh[tid] = min(xi + 1, W_F - 1);
    g_lx[tid] = x - (float)xi; g_hx[tid] = 1.0f - (x - (float)xi);
  }
  __syncthreads();

  const int c = ch * 256 + tid;
  for (int cell = 0; cell < 49; ++cell) {
    const int py = cell / 7;
    const int px = cell - py * 7;
    float acc = 0.0f;
#pragma unroll
    for (int sy = 0; sy < 2; ++sy) {
      const int iy = 2 * py + sy;
      if (!g_vy[iy]) continue;
      const float ly = g_ly[iy], hy = g_hy[iy];
      const int ry0i = g_yl[iy] * W_F, ry1i = g_yh[iy] * W_F;
#pragma unroll
      for (int sx = 0; sx < 2; ++sx) {
        const int ix = 2 * px + sx;
        if (!g_vx[ix]) continue;
        const float lx = g_lx[ix], hx = g_hx[ix];
        const float* b00 = ft + (size_t)(ry0i + g_xl[ix]) * C_N;
        const float* b01 = ft + (size_t)(ry0i + g_xh[ix]) * C_N;
        const float* b10 = ft + (size_t)(ry1i + g_xl[ix]) * C_N;
        const float* b11 = ft + (size_t)(ry1i + g_xh[ix]) * C_N;
        acc += (hy*hx)*b00[c] + (hy*lx)*b01[c] + (ly*hx)*b10[c] + (ly*lx)*b11[c];
      }
    }
    _Float16 h, l;
    split16(acc * 0.25f, h, l);
    hbuf[tid * 49 + cell] = h;
    lbuf[tid * 49 + cell] = l;
  }
  __syncthreads();

  const size_t base = (size_t)p * FIN + (size_t)ch * 12544;
  const uint4* hs = (const uint4*)hbuf;
  const uint4* ls = (const uint4*)lbuf;
  uint4* dh = (uint4*)(Xhi + base);
  uint4* dl = (uint4*)(Xlo + base);
  for (int k = tid; k < 1568; k += 256) { dh[k] = hs[k]; dl[k] = ls[k]; }
}

// ---------------- MFMA f16 3-pass split-K GEMM: out = A(M,K) * W(N,K)^T ----------------
__device__ __forceinline__ int swz(int slot, int ks) {
  return slot ^ ((slot >> 5) & 1) ^ (((slot >> 3) & 1) << 1) ^ ((ks & 1) << 2);
}

__global__ __launch_bounds__(256, 2) void gemm_f16_3p(
    const _Float16* __restrict__ Ahi, const _Float16* __restrict__ Alo,
    const float* __restrict__ Wt, float* __restrict__ Pt,
    int M, int K, int steps_per_z, int ldc)
{
  __shared__ _Float16 lds[16384];
  const int tid  = threadIdx.x;
  const int lane = tid & 63, wave = tid >> 6;
  const int wm = wave >> 1, wn = wave & 1;

  // XCD-aware bijective swizzle: give each XCD a contiguous logical range
  // (x fastest, z-major) so blocks sharing an A k-chunk / W tile share an L2.
  const int GX = gridDim.x, GY = gridDim.y;
  const int T  = GX * GY * gridDim.z;
  int flat = blockIdx.x + GX * (blockIdx.y + GY * blockIdx.z);
  if ((T & 7) == 0) flat = (flat & 7) * (T >> 3) + (flat >> 3);
  const int bx = flat % GX;
  const int by = (flat / GX) % GY;
  const int bz = flat / (GX * GY);

  const int m0 = bx * 128, n0 = by * 128;
  const int steps_total = K >> 5;
  const int s0 = bz * steps_per_z;
  const int s1 = min(s0 + steps_per_z, steps_total);

  f32x16 acc0[2][2], acc1[2][2];
#pragma unroll
  for (int a = 0; a < 2; ++a)
#pragma unroll
    for (int b = 0; b < 2; ++b) {
#pragma unroll
      for (int r = 0; r < 16; ++r) { acc0[a][b][r] = 0.f; acc1[a][b][r] = 0.f; }
    }

  const int srow = tid >> 2;
  const int j8   = tid & 3;
  const int ksW  = j8 >> 1, kc8 = j8 & 1;
  const int wslot = swz((kc8 << 5) | (srow & 31), ksW);

  for (int step = s0; step < s1; ++step) {
    const int kb = step << 5;
#pragma unroll
    for (int half = 0; half < 2; ++half) {
      const int row = srow + half * 64;
      const int mf  = row >> 5;
      const int gm  = m0 + row;
      uint4 vh = make_uint4(0,0,0,0), vl = make_uint4(0,0,0,0);
      if (gm < M) {
        vh = *reinterpret_cast<const uint4*>(Ahi + (size_t)gm * K + kb + j8 * 8);
        vl = *reinterpret_cast<const uint4*>(Alo + (size_t)gm * K + kb + j8 * 8);
      }
      const int base = (mf * 2 + ksW) * 512 + wslot * 8;
      *reinterpret_cast<uint4*>(&lds[base])        = vh;
      *reinterpret_cast<uint4*>(&lds[4096 + base]) = vl;
    }
#pragma unroll
    for (int half = 0; half < 2; ++half) {
      const int n = srow + half * 64;
      const float* wp = Wt + (size_t)(n0 + n) * K + kb + j8 * 8;
      const float4 f0 = *reinterpret_cast<const float4*>(wp);
      const float4 f1 = *reinterpret_cast<const float4*>(wp + 4);
      float fv[8] = {f0.x, f0.y, f0.z, f0.w, f1.x, f1.y, f1.z, f1.w};
      union { _Float16 h[8]; uint4 v; } uh, ul;
#pragma unroll
      for (int e = 0; e < 8; ++e) split16(fv[e], uh.h[e], ul.h[e]);
      const int nf = n >> 5;
      const int base = 8192 + (nf * 2 + ksW) * 512 + wslot * 8;
      *reinterpret_cast<uint4*>(&lds[base])        = uh.v;
      *reinterpret_cast<uint4*>(&lds[4096 + base]) = ul.v;
    }
    __syncthreads();
#pragma unroll
    for (int ks = 0; ks < 2; ++ks) {
      const int rslot = swz(lane, ks) * 8;
      half8 ah[2], al[2], bh[2], bl[2];
#pragma unroll
      for (int mi = 0; mi < 2; ++mi) {
        const int mf = wm * 2 + mi;
        ah[mi] = *reinterpret_cast<const half8*>(&lds[(mf * 2 + ks) * 512 + rslot]);
        al[mi] = *reinterpret_cast<const half8*>(&lds[4096 + (mf * 2 + ks) * 512 + rslot]);
      }
#pragma unroll
      for (int ni = 0; ni < 2; ++ni) {
        const int nf = wn * 2 + ni;
        bh[ni] = *reinterpret_cast<const half8*>(&lds[8192  + (nf * 2 + ks) * 512 + rslot]);
        bl[ni] = *reinterpret_cast<const half8*>(&lds[12288 + (nf * 2 + ks) * 512 + rslot]);
      }
#pragma unroll
      for (int mi = 0; mi < 2; ++mi)
#pragma unroll
        for (int ni = 0; ni < 2; ++ni) {
          acc0[mi][ni] = __builtin_amdgcn_mfma_f32_32x32x16_f16(ah[mi], bh[ni], acc0[mi][ni], 0, 0, 0);
          acc1[mi][ni] = __builtin_amdgcn_mfma_f32_32x32x16_f16(ah[mi], bl[ni], acc1[mi][ni], 0, 0, 0);
          acc1[mi][ni] = __builtin_amdgcn_mfma_f32_32x32x16_f16(al[mi], bh[ni], acc1[mi][ni], 0, 0, 0);
        }
    }
    __syncthreads();
  }
  const int col = lane & 31, rhi = lane >> 5;
  float* outp = Pt + (size_t)bz * ((size_t)M * ldc);
#pragma unroll
  for (int mi = 0; mi < 2; ++mi)
#pragma unroll
    for (int ni = 0; ni < 2; ++ni) {
      const int n = n0 + (wn * 2 + ni) * 32 + col;
      if (n >= ldc) continue;
#pragma unroll
      for (int r = 0; r < 16; ++r) {
        const int m = m0 + (wm * 2 + mi) * 32 + ((r & 3) + 8 * (r >> 2) + 4 * rhi);
        if (m < M) outp[(size_t)m * ldc + n] = acc0[mi][ni][r] + acc1[mi][ni][r] * LO_INV;
      }
    }
}

// ---------------- reduce split-K + bias (+relu) -> f32 and/or f16 hi/lo ----------------
__global__ __launch_bounds__(256) void reduce_bias(
    const float* __restrict__ Pt, const float* __restrict__ bias,
    float* __restrict__ out_f32, _Float16* __restrict__ out_hi, _Float16* __restrict__ out_lo,
    int MN, int KS, int nmask, int relu)
{
  int i = blockIdx.x * 256 + threadIdx.x;
  if (i >= MN) return;
  float s = 0.0f;
  for (int k = 0; k < KS; ++k) s += Pt[(size_t)k * MN + i];
  s += bias[i & nmask];
  if (relu) s = fmaxf(s, 0.0f);
  if (out_f32) out_f32[i] = s;
  if (out_hi) {
    _Float16 h, l; split16(s, h, l);
    out_hi[i] = h; out_lo[i] = l;
  }
}

// ---------------- pad [cls_w; reg_w; 0] into Wpad[128][1024], bias likewise ----------------
__global__ __launch_bounds__(256) void prep_head(const float* __restrict__ cls_w,
                                                 const float* __restrict__ cls_b,
                                                 const float* __restrict__ reg_w,
                                                 const float* __restrict__ reg_b,
                                                 float* __restrict__ Wpad,
                                                 float* __restrict__ bpad) {
  const int row = blockIdx.x;
  const int t = threadIdx.x;
  const float* src = (row < NCLS) ? (cls_w + (size_t)row * D_N)
                   : (row < 105)  ? (reg_w + (size_t)(row - NCLS) * D_N) : nullptr;
  float4 v = make_float4(0.f, 0.f, 0.f, 0.f);
  if (src) v = reinterpret_cast<const float4*>(src)[t];
  reinterpret_cast<float4*>(Wpad + (size_t)row * D_N)[t] = v;
  if (t == 0)
    bpad[row] = (row < NCLS) ? cls_b[row] : (row < 105) ? reg_b[row - NCLS] : 0.0f;
}

// ---------------- decode: softmax over 21 logits + box decode + validity ----------------
__global__ __launch_bounds__(64) void decode_kernel(const float* __restrict__ logits,
                                                    const float* __restrict__ props,
                                                    float* __restrict__ cboxes,
                                                    float* __restrict__ cscores,
                                                    int* __restrict__ cvalid) {
  const int p = blockIdx.x;
  const int lane = threadIdx.x;
  const float* lg = logits + (size_t)p * NHEAD;

  float s = (lane < NCLS) ? lg[lane] : -__builtin_inff();
  float mx = s;
#pragma unroll
  for (int off = 32; off > 0; off >>= 1) mx = fmaxf(mx, __shfl_xor(mx, off));
  float e = (lane < NCLS) ? expf(s - mx) : 0.0f;
  float sum = e;
#pragma unroll
  for (int off = 32; off > 0; off >>= 1) sum += __shfl_xor(sum, off);
  const float sm = e / sum;

  if (lane >= 1 && lane < NCLS) {
    const int c = lane;
    const float x0 = props[p*4+0], y0 = props[p*4+1], x1 = props[p*4+2], y1 = props[p*4+3];
    const float w = x1 - x0, hh = y1 - y0;
    const float cx = x0 + 0.5f * w, cy = y0 + 0.5f * hh;
    const float dx = lg[NCLS + c*4 + 0];
    const float dy = lg[NCLS + c*4 + 1];
    const float dw = fminf(lg[NCLS + c*4 + 2], BBOX_CLIP_F);
    const float dh = fminf(lg[NCLS + c*4 + 3], BBOX_CLIP_F);
    const float pcx = dx * w + cx, pcy = dy * hh + cy;
    const float pw = expf(dw) * w, ph = expf(dh) * hh;
    float bx0 = pcx - 0.5f * pw, by0 = pcy - 0.5f * ph;
    float bx1 = pcx + 0.5f * pw, by1 = pcy + 0.5f * ph;
    bx0 = fminf(fmaxf(bx0, 0.0f), W_IMG);
    by0 = fminf(fmaxf(by0, 0.0f), H_IMG);
    bx1 = fminf(fmaxf(bx1, 0.0f), W_IMG);
    by1 = fminf(fmaxf(by1, 0.0f), H_IMG);
    const int idx = p * 20 + (c - 1);
    cboxes[idx*4+0] = bx0; cboxes[idx*4+1] = by0;
    cboxes[idx*4+2] = bx1; cboxes[idx*4+3] = by1;
    const bool valid = (sm > 0.05f) && ((bx1 - bx0) >= 1.0f) && ((by1 - by0) >= 1.0f);
    cscores[idx] = sm;
    cvalid[idx] = valid ? 1 : 0;
  }
}

// ---------------- compact valid candidates (order-independent: key embeds idx) ----------------
__global__ void zero_counter(int* c) { if (threadIdx.x == 0 && blockIdx.x == 0) *c = 0; }

__global__ __launch_bounds__(256) void compact_kernel(const float* __restrict__ cscores,
                                                      const int* __restrict__ cvalid,
                                                      unsigned long long* __restrict__ ckeys,
                                                      int* __restrict__ vcount) {
  int i = blockIdx.x * 256 + threadIdx.x;
  if (i >= NCAND) return;
  if (cvalid[i]) {
    int pos = atomicAdd(vcount, 1);
    unsigned u = __float_as_uint(cscores[i]);
    ckeys[pos] = ((unsigned long long)(~u) << 32) | (unsigned)i;
  }
}

// ---------------- bitonic sort over next-pow2(V) + gather sorted candidate arrays ----------------
__global__ __launch_bounds__(1024) void sort_gather(const unsigned long long* __restrict__ ckeys,
                                                    const int* __restrict__ vcount,
                                                    const float* __restrict__ cboxes,
                                                    float4* __restrict__ sbox,
                                                    float* __restrict__ sscore,
                                                    int* __restrict__ slab) {
  __shared__ unsigned long long keys[8192];
  const int tid = threadIdx.x;
  const int V = *vcount;
  int Npad = 64; while (Npad < V) Npad <<= 1;
  for (int i = tid; i < Npad; i += 1024)
    keys[i] = (i < V) ? ckeys[i] : ~0ULL;
  __syncthreads();
  for (int kk = 2; kk <= Npad; kk <<= 1) {
    for (int j = kk >> 1; j > 0; j >>= 1) {
      for (int i = tid; i < Npad; i += 1024) {
        int ij = i ^ j;
        if (ij > i) {
          unsigned long long a = keys[i], b = keys[ij];
          bool up = ((i & kk) == 0);
          if ((a > b) == up) { keys[i] = b; keys[ij] = a; }
        }
      }
      __syncthreads();
    }
  }
  for (int i = tid; i < V; i += 1024) {
    unsigned long long key = keys[i];
    int idx = (int)(key & 0xffffffffu);
    sbox[i]   = *reinterpret_cast<const float4*>(&cboxes[(size_t)idx * 4]);
    sscore[i] = __uint_as_float(~(unsigned)(key >> 32));
    slab[i]   = idx % 20;
  }
}

// ---------------- suppression matrix: mask[i][w] bit j = (j>i, same label, IoU>0.5) ----------------
__global__ __launch_bounds__(256) void iou_matrix(const float4* __restrict__ sbox,
                                                  const int* __restrict__ slab,
                                                  const int* __restrict__ vcount,
                                                  unsigned long long* __restrict__ mask) {
  const int V = *vcount;
  const int i = blockIdx.x * 4 + (threadIdx.x >> 6);
  const int lane = threadIdx.x & 63;
  if (i >= V) return;
  const float4 bi = sbox[i];
  const int li = slab[i];
  const float ai = (bi.z - bi.x) * (bi.w - bi.y);
  const int nw = (V + 63) >> 6;
  for (int w = 0; w < nw; ++w) {
    const int j = (w << 6) + lane;
    bool sup = false;
    if (j > i && j < V && slab[j] == li) {
      const float4 bj = sbox[j];
      const float iw = fminf(bi.z, bj.z) - fmaxf(bi.x, bj.x);
      const float ih = fminf(bi.w, bj.w) - fmaxf(bi.y, bj.y);
      const float inter = fmaxf(iw, 0.0f) * fmaxf(ih, 0.0f);
      const float aj = (bj.z - bj.x) * (bj.w - bj.y);
      sup = inter / (ai + aj - inter) > 0.5f;
    }
    const unsigned long long m = __ballot(sup);
    if (lane == 0) mask[(size_t)i * NW + w] = m;
  }
}

// ---------------- NMS scan: single wave, live-mask in registers, no barriers ----------------
__global__ __launch_bounds__(64) void nms_scan(const float4* __restrict__ sbox,
                                               const float* __restrict__ sscore,
                                               const int* __restrict__ slab,
                                               const int* __restrict__ vcount,
                                               const unsigned long long* __restrict__ mask,
                                               float* __restrict__ out) {
  const int lane = threadIdx.x;
  const int V = min(*vcount, NCAND);
  unsigned long long live0 = ~0ULL, live1 = ~0ULL;   // words [lane], [64+lane]
  int nk = 0;
  for (int i = 0; i < V && nk < 100; ++i) {
    const int wi = i >> 6, bi = i & 63;
    union { unsigned long long u; uint2 v; } t;
    t.u = (wi < 64) ? live0 : live1;
    const int src = (wi < 64) ? wi : (wi - 64);
    const unsigned lo = __shfl(t.v.x, src);
    const unsigned hi = __shfl(t.v.y, src);
    const unsigned long long wv = ((unsigned long long)hi << 32) | lo;
    if ((wv >> bi) & 1ULL) {
      if (lane == 0) {
        const float4 bb = sbox[i];
        out[nk*4+0] = bb.x; out[nk*4+1] = bb.y; out[nk*4+2] = bb.z; out[nk*4+3] = bb.w;
        out[400 + nk] = (float)slab[i];
        out[500 + nk] = sscore[i];
      }
      const unsigned long long* mrow = mask + (size_t)i * NW;
      live0 &= ~mrow[lane];
      if (lane < NW - 64) live1 &= ~mrow[64 + lane];
      nk++;
    }
  }
  for (int r = nk + lane; r < 100; r += 64) {
    out[r*4+0] = 0.0f; out[r*4+1] = 0.0f; out[r*4+2] = 0.0f; out[r*4+3] = 0.0f;
    out[400 + r] = -1.0f;
    out[500 + r] = 0.0f;
  }
}

// ---------------- launch ----------------
extern "C" void kernel_launch(void* const* d_in, const int* in_sizes, int n_in,
                              void* d_out, int out_size, void* d_ws, size_t ws_size,
                              hipStream_t stream) {
  const float* feat   = (const float*)d_in[1];
  const float* props  = (const float*)d_in[2];
  const float* fc6_w  = (const float*)d_in[3];
  const float* fc6_b  = (const float*)d_in[4];
  const float* fc7_w  = (const float*)d_in[5];
  const float* fc7_b  = (const float*)d_in[6];
  const float* cls_w  = (const float*)d_in[7];
  const float* cls_b  = (const float*)d_in[8];
  const float* reg_w  = (const float*)d_in[9];
  const float* reg_b  = (const float*)d_in[10];

  char* ws = (char*)d_ws;
  size_t off = 0;
  auto alloc = [&](size_t bytes) -> void* {
    void* p = ws + off;
    off += (bytes + 255) & ~(size_t)255;
    return p;
  };

  _Float16* Xhi  = (_Float16*)alloc((size_t)P_N * FIN * 2);
  _Float16* Xlo  = (_Float16*)alloc((size_t)P_N * FIN * 2);
  float*    Pt   = (float*)alloc((size_t)KS6 * P_N * D_N * 4);   // 51.6 MB
  _Float16* h6hi = (_Float16*)alloc((size_t)P_N * D_N * 2);
  _Float16* h6lo = (_Float16*)alloc((size_t)P_N * D_N * 2);
  _Float16* h7hi = (_Float16*)alloc((size_t)P_N * D_N * 2);
  _Float16* h7lo = (_Float16*)alloc((size_t)P_N * D_N * 2);
  float*    Wpad = (float*)alloc((size_t)NHEAD * D_N * 4);
  float*    bpad = (float*)alloc((size_t)NHEAD * 4);
  float*  logits = (float*)alloc((size_t)P_N * NHEAD * 4);
  float*  cboxes = (float*)alloc((size_t)NCAND * 4 * 4);
  float* cscores = (float*)alloc((size_t)NCAND * 4);
  int*    cvalid = (int*)alloc((size_t)NCAND * 4);
  unsigned long long* ckeys = (unsigned long long*)alloc((size_t)NCAND * 8);
  float4*   sbox = (float4*)alloc((size_t)NCAND * 16);
  float*  sscore = (float*)alloc((size_t)NCAND * 4);
  int*      slab = (int*)alloc((size_t)NCAND * 4);
  unsigned long long* supmask = (unsigned long long*)alloc((size_t)NCAND * NW * 8); // 4.6 MB
  int*    vcount = (int*)alloc(256);
  // ft (6.9 MB) aliases Pt (51.6 MB): Pt first written after roi_align consumed ft.
  float* ft = Pt;
  (void)ws_size; (void)in_sizes; (void)n_in; (void)out_size;

  // 0) pad head weights/bias
  prep_head<<<NHEAD, 256, 0, stream>>>(cls_w, cls_b, reg_w, reg_b, Wpad, bpad);
  // 1) feat (C,HW) -> (HW,C)
  transpose_feat<<<dim3((HW_F + 31) / 32, C_N / 32), dim3(32, 8), 0, stream>>>(feat, ft);
  // 2) ROI align -> X hi/lo f16
  roi_align_k<<<dim3(P_N, 2), 256, 0, stream>>>(ft, props, Xhi, Xlo);
  // 3) fc6
  gemm_f16_3p<<<dim3(3, 8, KS6), 256, 0, stream>>>(Xhi, Xlo, fc6_w, Pt, P_N, FIN, STEPS6_PER_Z, D_N);
  reduce_bias<<<(P_N * D_N + 255) / 256, 256, 0, stream>>>(
      Pt, fc6_b, nullptr, h6hi, h6lo, P_N * D_N, KS6, D_N - 1, 1);
  // 4) fc7
  gemm_f16_3p<<<dim3(3, 8, KS7), 256, 0, stream>>>(h6hi, h6lo, fc7_w, Pt, P_N, D_N, STEPS7_PER_Z, D_N);
  reduce_bias<<<(P_N * D_N + 255) / 256, 256, 0, stream>>>(
      Pt, fc7_b, nullptr, h7hi, h7lo, P_N * D_N, KS7, D_N - 1, 1);
  // 5) head GEMM (N=128 padded) + logits reduce (no relu)
  gemm_f16_3p<<<dim3(3, 1, KSH), 256, 0, stream>>>(h7hi, h7lo, Wpad, Pt, P_N, D_N, STEPSH_PER_Z, NHEAD);
  reduce_bias<<<(P_N * NHEAD + 255) / 256, 256, 0, stream>>>(
      Pt, bpad, logits, nullptr, nullptr, P_N * NHEAD, KSH, NHEAD - 1, 0);
  // 6) softmax + decode + validity
  decode_kernel<<<P_N, 64, 0, stream>>>(logits, props, cboxes, cscores, cvalid);
  // 7) compact -> sort -> gather
  zero_counter<<<1, 1, 0, stream>>>(vcount);
  compact_kernel<<<(NCAND + 255) / 256, 256, 0, stream>>>(cscores, cvalid, ckeys, vcount);
  sort_gather<<<1, 1024, 0, stream>>>(ckeys, vcount, cboxes, sbox, sscore, slab);
  // 8) suppression matrix (parallel) + single-wave NMS bit-scan
  iou_matrix<<<(NCAND + 3) / 4, 256, 0, stream>>>(sbox, slab, vcount, supmask);
  nms_scan<<<1, 64, 0, stream>>>(sbox, sscore, slab, vcount, supmask, (float*)d_out);
}

// Round 6
// 343.246 us; speedup vs baseline: 1.0048x; 1.0048x over previous
//
#include <hip/hip_runtime.h>
#include <hip/hip_bf16.h>
#include <math.h>

// ---------------- problem constants ----------------
#define P_N   300
#define C_N   512
#define H_F   50
#define W_F   67
#define HW_F  3350
#define D_N   1024
#define FIN   25088
#define NCLS  21
#define NCAND 6000
#define W_IMG 1072.0f
#define H_IMG 800.0f
#define BBOX_CLIP_F 4.135166556742356f
#define KS6   42
#define STEPS6_PER_Z 19
#define KS7   16
#define STEPS7_PER_Z 2
#define KSH   16
#define STEPSH_PER_Z 2
#define NHEAD 128
#define NW    96            // suppression-mask words per row (96*64 = 6144 >= NCAND)
#define A_SCALE 16.0f       // A-side split scale (keeps residuals in f16 normal range)
#define B_SCALE 256.0f      // B-side split scale
#define O_SCALE (1.0f / 4096.0f)

typedef __attribute__((ext_vector_type(8)))  _Float16 half8;
typedef __attribute__((ext_vector_type(16))) float    f32x16;

// split f into f16 hi + f16 residual of (f * A_SCALE); A*B recombines at 1/(A*B scale)
__device__ __forceinline__ void splitA(float f, _Float16& h, _Float16& l) {
  float fs = f * A_SCALE;
  h = (_Float16)fs;
  l = (_Float16)(fs - (float)h);
}

// ---------------- feat (C,H,W) -> (H*W, C) transpose ----------------
__global__ __launch_bounds__(256) void transpose_feat(const float* __restrict__ feat,
                                                      float* __restrict__ ft) {
  __shared__ float tile[32][33];
  const int s0 = blockIdx.x * 32, c0 = blockIdx.y * 32;
  const int tx = threadIdx.x, ty = threadIdx.y;
  for (int r = ty; r < 32; r += 8) {
    int c = c0 + r, s = s0 + tx;
    tile[r][tx] = (s < HW_F) ? feat[(size_t)c * HW_F + s] : 0.0f;
  }
  __syncthreads();
  for (int r = ty; r < 32; r += 8) {
    int s = s0 + r, c = c0 + tx;
    if (s < HW_F) ft[(size_t)s * C_N + c] = tile[tx][r];
  }
}

// ---------------- ROI align: block per (proposal, channel-half) ----------------
__global__ __launch_bounds__(256) void roi_align_k(const float* __restrict__ ft,
                                                   const float* __restrict__ rois,
                                                   _Float16* __restrict__ Xhi,
                                                   _Float16* __restrict__ Xlo) {
  __shared__ _Float16 hbuf[12544] __attribute__((aligned(16)));
  __shared__ _Float16 lbuf[12544] __attribute__((aligned(16)));
  __shared__ int   g_yl[14], g_yh[14], g_xl[14], g_xh[14];
  __shared__ float g_ly[14], g_hy[14], g_lx[14], g_hx[14];
  __shared__ int   g_vy[14], g_vx[14];

  const int p   = blockIdx.x;
  const int ch  = blockIdx.y;
  const int tid = threadIdx.x;

  if (tid < 14) {
    const float rx0 = rois[p*4+0], ry0 = rois[p*4+1], rx1 = rois[p*4+2], ry1 = rois[p*4+3];
    const float x0r = rx0 * 0.0625f - 0.5f;
    const float y0r = ry0 * 0.0625f - 0.5f;
    const float bw  = (rx1 - rx0) * 0.0625f * (1.0f / 7.0f);
    const float bh  = (ry1 - ry0) * 0.0625f * (1.0f / 7.0f);
    const float t   = ((float)tid + 0.5f) * 0.5f;

    const float ys = y0r + bh * t;
    g_vy[tid] = (ys >= -1.0f) && (ys <= (float)H_F);
    float y = fminf(fmaxf(ys, 0.0f), (float)(H_F - 1));
    int yi = (int)floorf(y);
    g_yl[tid] = yi; g_yh[tid] = min(yi + 1, H_F - 1);
    g_ly[tid] = y - (float)yi; g_hy[tid] = 1.0f - (y - (float)yi);

    const float xs = x0r + bw * t;
    g_vx[tid] = (xs >= -1.0f) && (xs <= (float)W_F);
    float x = fminf(fmaxf(xs, 0.0f), (float)(W_F - 1));
    int xi = (int)floorf(x);
    g_xl[tid] = xi; g_xh[tid] = min(xi + 1, W_F - 1);
    g_lx[tid] = x - (float)xi; g_hx[tid] = 1.0f - (x - (float)xi);
  }
  __syncthreads();

  const int c = ch * 256 + tid;
  for (int cell = 0; cell < 49; ++cell) {
    const int py = cell / 7;
    const int px = cell - py * 7;
    float acc = 0.0f;
#pragma unroll
    for (int sy = 0; sy < 2; ++sy) {
      const int iy = 2 * py + sy;
      if (!g_vy[iy]) continue;
      const float ly = g_ly[iy], hy = g_hy[iy];
      const int ry0i = g_yl[iy] * W_F, ry1i = g_yh[iy] * W_F;
#pragma unroll
      for (int sx = 0; sx < 2; ++sx) {
        const int ix = 2 * px + sx;
        if (!g_vx[ix]) continue;
        const float lx = g_lx[ix], hx = g_hx[ix];
        const float* b00 = ft + (size_t)(ry0i + g_xl[ix]) * C_N;
        const float* b01 = ft + (size_t)(ry0i + g_xh[ix]) * C_N;
        const float* b10 = ft + (size_t)(ry1i + g_xl[ix]) * C_N;
        const float* b11 = ft + (size_t)(ry1i + g_xh[ix]) * C_N;
        acc += (hy*hx)*b00[c] + (hy*lx)*b01[c] + (ly*hx)*b10[c] + (ly*lx)*b11[c];
      }
    }
    _Float16 h, l;
    splitA(acc * 0.25f, h, l);
    hbuf[tid * 49 + cell] = h;
    lbuf[tid * 49 + cell] = l;
  }
  __syncthreads();

  const size_t base = (size_t)p * FIN + (size_t)ch * 12544;
  const uint4* hs = (const uint4*)hbuf;
  const uint4* ls = (const uint4*)lbuf;
  uint4* dh = (uint4*)(Xhi + base);
  uint4* dl = (uint4*)(Xlo + base);
  for (int k = tid; k < 1568; k += 256) { dh[k] = hs[k]; dl[k] = ls[k]; }
}

// ---------------- MFMA f16 3-product single-acc split-K GEMM: out = A(M,K) * W(N,K)^T ----------------
__device__ __forceinline__ int swz(int slot, int ks) {
  return slot ^ ((slot >> 5) & 1) ^ (((slot >> 3) & 1) << 1) ^ ((ks & 1) << 2);
}

__global__ __launch_bounds__(256, 3) void gemm_f16_3p(
    const _Float16* __restrict__ Ahi, const _Float16* __restrict__ Alo,
    const float* __restrict__ Wt, float* __restrict__ Pt,
    int M, int K, int steps_per_z, int ldc)
{
  __shared__ _Float16 lds[16384];
  const int tid  = threadIdx.x;
  const int lane = tid & 63, wave = tid >> 6;
  const int wm = wave >> 1, wn = wave & 1;

  // XCD-aware bijective swizzle (grid divisible by 8): contiguous logical range per XCD.
  const int GX = gridDim.x, GY = gridDim.y;
  const int T  = GX * GY * gridDim.z;
  int flat = blockIdx.x + GX * (blockIdx.y + GY * blockIdx.z);
  if ((T & 7) == 0) flat = (flat & 7) * (T >> 3) + (flat >> 3);
  const int bx = flat % GX;
  const int by = (flat / GX) % GY;
  const int bz = flat / (GX * GY);

  const int m0 = bx * 128, n0 = by * 128;
  const int steps_total = K >> 5;
  const int s0 = bz * steps_per_z;
  const int s1 = min(s0 + steps_per_z, steps_total);

  f32x16 acc[2][2];
#pragma unroll
  for (int a = 0; a < 2; ++a)
#pragma unroll
    for (int b = 0; b < 2; ++b)
#pragma unroll
      for (int r = 0; r < 16; ++r) acc[a][b][r] = 0.f;

  const int srow = tid >> 2;
  const int j8   = tid & 3;
  const int ksW  = j8 >> 1, kc8 = j8 & 1;
  const int wslot = swz((kc8 << 5) | (srow & 31), ksW);

  for (int step = s0; step < s1; ++step) {
    const int kb = step << 5;
#pragma unroll
    for (int half = 0; half < 2; ++half) {
      const int row = srow + half * 64;
      const int mf  = row >> 5;
      const int gm  = m0 + row;
      uint4 vh = make_uint4(0,0,0,0), vl = make_uint4(0,0,0,0);
      if (gm < M) {
        vh = *reinterpret_cast<const uint4*>(Ahi + (size_t)gm * K + kb + j8 * 8);
        vl = *reinterpret_cast<const uint4*>(Alo + (size_t)gm * K + kb + j8 * 8);
      }
      const int base = (mf * 2 + ksW) * 512 + wslot * 8;
      *reinterpret_cast<uint4*>(&lds[base])        = vh;
      *reinterpret_cast<uint4*>(&lds[4096 + base]) = vl;
    }
#pragma unroll
    for (int half = 0; half < 2; ++half) {
      const int n = srow + half * 64;
      const float* wp = Wt + (size_t)(n0 + n) * K + kb + j8 * 8;
      const float4 f0 = *reinterpret_cast<const float4*>(wp);
      const float4 f1 = *reinterpret_cast<const float4*>(wp + 4);
      float fv[8] = {f0.x, f0.y, f0.z, f0.w, f1.x, f1.y, f1.z, f1.w};
      union { _Float16 h[8]; uint4 v; } uh, ul;
#pragma unroll
      for (int e = 0; e < 8; ++e) {
        float fs = fv[e] * B_SCALE;
        uh.h[e] = (_Float16)fs;
        ul.h[e] = (_Float16)(fs - (float)uh.h[e]);
      }
      const int nf = n >> 5;
      const int base = 8192 + (nf * 2 + ksW) * 512 + wslot * 8;
      *reinterpret_cast<uint4*>(&lds[base])        = uh.v;
      *reinterpret_cast<uint4*>(&lds[4096 + base]) = ul.v;
    }
    __syncthreads();
#pragma unroll
    for (int ks = 0; ks < 2; ++ks) {
      const int rslot = swz(lane, ks) * 8;
      half8 ah[2], al[2], bh[2], bl[2];
#pragma unroll
      for (int mi = 0; mi < 2; ++mi) {
        const int mf = wm * 2 + mi;
        ah[mi] = *reinterpret_cast<const half8*>(&lds[(mf * 2 + ks) * 512 + rslot]);
        al[mi] = *reinterpret_cast<const half8*>(&lds[4096 + (mf * 2 + ks) * 512 + rslot]);
      }
#pragma unroll
      for (int ni = 0; ni < 2; ++ni) {
        const int nf = wn * 2 + ni;
        bh[ni] = *reinterpret_cast<const half8*>(&lds[8192  + (nf * 2 + ks) * 512 + rslot]);
        bl[ni] = *reinterpret_cast<const half8*>(&lds[12288 + (nf * 2 + ks) * 512 + rslot]);
      }
#pragma unroll
      for (int mi = 0; mi < 2; ++mi)
#pragma unroll
        for (int ni = 0; ni < 2; ++ni) {
          acc[mi][ni] = __builtin_amdgcn_mfma_f32_32x32x16_f16(ah[mi], bh[ni], acc[mi][ni], 0, 0, 0);
          acc[mi][ni] = __builtin_amdgcn_mfma_f32_32x32x16_f16(ah[mi], bl[ni], acc[mi][ni], 0, 0, 0);
          acc[mi][ni] = __builtin_amdgcn_mfma_f32_32x32x16_f16(al[mi], bh[ni], acc[mi][ni], 0, 0, 0);
        }
    }
    __syncthreads();
  }
  const int col = lane & 31, rhi = lane >> 5;
  float* outp = Pt + (size_t)bz * ((size_t)M * ldc);
#pragma unroll
  for (int mi = 0; mi < 2; ++mi)
#pragma unroll
    for (int ni = 0; ni < 2; ++ni) {
      const int n = n0 + (wn * 2 + ni) * 32 + col;
      if (n >= ldc) continue;
#pragma unroll
      for (int r = 0; r < 16; ++r) {
        const int m = m0 + (wm * 2 + mi) * 32 + ((r & 3) + 8 * (r >> 2) + 4 * rhi);
        if (m < M) outp[(size_t)m * ldc + n] = acc[mi][ni][r] * O_SCALE;
      }
    }
}

// ---------------- reduce split-K + bias (+relu) -> f32 and/or f16 hi/lo ----------------
__global__ __launch_bounds__(256) void reduce_bias(
    const float* __restrict__ Pt, const float* __restrict__ bias,
    float* __restrict__ out_f32, _Float16* __restrict__ out_hi, _Float16* __restrict__ out_lo,
    int MN, int KS, int nmask, int relu)
{
  int i = blockIdx.x * 256 + threadIdx.x;
  if (i >= MN) return;
  float s = 0.0f;
  for (int k = 0; k < KS; ++k) s += Pt[(size_t)k * MN + i];
  s += bias[i & nmask];
  if (relu) s = fmaxf(s, 0.0f);
  if (out_f32) out_f32[i] = s;
  if (out_hi) {
    _Float16 h, l; splitA(s, h, l);
    out_hi[i] = h; out_lo[i] = l;
  }
}

// ---------------- pad [cls_w; reg_w; 0] into Wpad[128][1024], bias likewise; zero vcount ----------------
__global__ __launch_bounds__(256) void prep_head(const float* __restrict__ cls_w,
                                                 const float* __restrict__ cls_b,
                                                 const float* __restrict__ reg_w,
                                                 const float* __restrict__ reg_b,
                                                 float* __restrict__ Wpad,
                                                 float* __restrict__ bpad,
                                                 int* __restrict__ vcount) {
  const int row = blockIdx.x;
  const int t = threadIdx.x;
  if (row == 0 && t == 0) *vcount = 0;
  const float* src = (row < NCLS) ? (cls_w + (size_t)row * D_N)
                   : (row < 105)  ? (reg_w + (size_t)(row - NCLS) * D_N) : nullptr;
  float4 v = make_float4(0.f, 0.f, 0.f, 0.f);
  if (src) v = reinterpret_cast<const float4*>(src)[t];
  reinterpret_cast<float4*>(Wpad + (size_t)row * D_N)[t] = v;
  if (t == 0)
    bpad[row] = (row < NCLS) ? cls_b[row] : (row < 105) ? reg_b[row - NCLS] : 0.0f;
}

// ---------------- decode: softmax + box decode + validity + compact (fused) ----------------
__global__ __launch_bounds__(64) void decode_kernel(const float* __restrict__ logits,
                                                    const float* __restrict__ props,
                                                    float* __restrict__ cboxes,
                                                    unsigned long long* __restrict__ ckeys,
                                                    int* __restrict__ vcount) {
  const int p = blockIdx.x;
  const int lane = threadIdx.x;
  const float* lg = logits + (size_t)p * NHEAD;

  float s = (lane < NCLS) ? lg[lane] : -__builtin_inff();
  float mx = s;
#pragma unroll
  for (int off = 32; off > 0; off >>= 1) mx = fmaxf(mx, __shfl_xor(mx, off));
  float e = (lane < NCLS) ? expf(s - mx) : 0.0f;
  float sum = e;
#pragma unroll
  for (int off = 32; off > 0; off >>= 1) sum += __shfl_xor(sum, off);
  const float sm = e / sum;

  if (lane >= 1 && lane < NCLS) {
    const int c = lane;
    const float x0 = props[p*4+0], y0 = props[p*4+1], x1 = props[p*4+2], y1 = props[p*4+3];
    const float w = x1 - x0, hh = y1 - y0;
    const float cx = x0 + 0.5f * w, cy = y0 + 0.5f * hh;
    const float dx = lg[NCLS + c*4 + 0];
    const float dy = lg[NCLS + c*4 + 1];
    const float dw = fminf(lg[NCLS + c*4 + 2], BBOX_CLIP_F);
    const float dh = fminf(lg[NCLS + c*4 + 3], BBOX_CLIP_F);
    const float pcx = dx * w + cx, pcy = dy * hh + cy;
    const float pw = expf(dw) * w, ph = expf(dh) * hh;
    float bx0 = pcx - 0.5f * pw, by0 = pcy - 0.5f * ph;
    float bx1 = pcx + 0.5f * pw, by1 = pcy + 0.5f * ph;
    bx0 = fminf(fmaxf(bx0, 0.0f), W_IMG);
    by0 = fminf(fmaxf(by0, 0.0f), H_IMG);
    bx1 = fminf(fmaxf(bx1, 0.0f), W_IMG);
    by1 = fminf(fmaxf(by1, 0.0f), H_IMG);
    const int idx = p * 20 + (c - 1);
    cboxes[idx*4+0] = bx0; cboxes[idx*4+1] = by0;
    cboxes[idx*4+2] = bx1; cboxes[idx*4+3] = by1;
    const bool valid = (sm > 0.05f) && ((bx1 - bx0) >= 1.0f) && ((by1 - by0) >= 1.0f);
    if (valid) {
      int pos = atomicAdd(vcount, 1);
      unsigned u = __float_as_uint(sm);
      ckeys[pos] = ((unsigned long long)(~u) << 32) | (unsigned)idx;  // desc score, asc idx
    }
  }
}

// ---------------- bitonic sort over next-pow2(V) + gather sorted candidate arrays ----------------
__global__ __launch_bounds__(1024) void sort_gather(const unsigned long long* __restrict__ ckeys,
                                                    const int* __restrict__ vcount,
                                                    const float* __restrict__ cboxes,
                                                    float4* __restrict__ sbox,
                                                    float* __restrict__ sscore,
                                                    int* __restrict__ slab) {
  __shared__ unsigned long long keys[8192];
  const int tid = threadIdx.x;
  const int V = *vcount;
  int Npad = 64; while (Npad < V) Npad <<= 1;
  for (int i = tid; i < Npad; i += 1024)
    keys[i] = (i < V) ? ckeys[i] : ~0ULL;
  __syncthreads();
  for (int kk = 2; kk <= Npad; kk <<= 1) {
    for (int j = kk >> 1; j > 0; j >>= 1) {
      for (int i = tid; i < Npad; i += 1024) {
        int ij = i ^ j;
        if (ij > i) {
          unsigned long long a = keys[i], b = keys[ij];
          bool up = ((i & kk) == 0);
          if ((a > b) == up) { keys[i] = b; keys[ij] = a; }
        }
      }
      __syncthreads();
    }
  }
  for (int i = tid; i < V; i += 1024) {
    unsigned long long key = keys[i];
    int idx = (int)(key & 0xffffffffu);
    sbox[i]   = *reinterpret_cast<const float4*>(&cboxes[(size_t)idx * 4]);
    sscore[i] = __uint_as_float(~(unsigned)(key >> 32));
    slab[i]   = idx % 20;
  }
}

// ---------------- suppression matrix: mask[i][w] bit j = (j>i, same label, IoU>0.5) ----------------
__global__ __launch_bounds__(256) void iou_matrix(const float4* __restrict__ sbox,
                                                  const int* __restrict__ slab,
                                                  const int* __restrict__ vcount,
                                                  unsigned long long* __restrict__ mask) {
  const int V = *vcount;
  const int i = blockIdx.x * 4 + (threadIdx.x >> 6);
  const int lane = threadIdx.x & 63;
  if (i >= V) return;
  const float4 bi = sbox[i];
  const int li = slab[i];
  const float ai = (bi.z - bi.x) * (bi.w - bi.y);
  const int nw = (V + 63) >> 6;
  for (int w = 0; w < nw; ++w) {
    const int j = (w << 6) + lane;
    bool sup = false;
    if (j > i && j < V && slab[j] == li) {
      const float4 bj = sbox[j];
      const float iw = fminf(bi.z, bj.z) - fmaxf(bi.x, bj.x);
      const float ih = fminf(bi.w, bj.w) - fmaxf(bi.y, bj.y);
      const float inter = fmaxf(iw, 0.0f) * fmaxf(ih, 0.0f);
      const float aj = (bj.z - bj.x) * (bj.w - bj.y);
      sup = inter / (ai + aj - inter) > 0.5f;
    }
    const unsigned long long m = __ballot(sup);
    if (lane == 0) mask[(size_t)i * NW + w] = m;
  }
}

// ---------------- NMS scan: single wave, word-skipping bit-scan over live mask ----------------
__device__ __forceinline__ unsigned long long bcast_live(unsigned long long live0,
                                                         unsigned long long live1, int w) {
  union { unsigned long long u; uint2 v; } t;
  t.u = (w < 64) ? live0 : live1;
  const int src = w & 63;
  const unsigned lo = __shfl(t.v.x, src);
  const unsigned hi = __shfl(t.v.y, src);
  return ((unsigned long long)hi << 32) | lo;
}

__global__ __launch_bounds__(64) void nms_scan(const float4* __restrict__ sbox,
                                               const float* __restrict__ sscore,
                                               const int* __restrict__ slab,
                                               const int* __restrict__ vcount,
                                               const unsigned long long* __restrict__ mask,
                                               float* __restrict__ out) {
  const int lane = threadIdx.x;
  const int V = min(*vcount, NCAND);
  const int nw = (V + 63) >> 6;
  unsigned long long live0 = ~0ULL, live1 = ~0ULL;   // words [lane], [64+lane]
  int nk = 0;
  for (int w = 0; w < nw && nk < 100; ++w) {
    const int nb = V - (w << 6);                      // valid bits in this word
    const unsigned long long vmask = (nb >= 64) ? ~0ULL : ((1ULL << nb) - 1ULL);
    unsigned long long wv = bcast_live(live0, live1, w) & vmask;
    while (wv && nk < 100) {
      const int b = __ffsll((long long)wv) - 1;
      const int i = (w << 6) + b;
      if (lane == 0) {
        const float4 bb = sbox[i];
        out[nk*4+0] = bb.x; out[nk*4+1] = bb.y; out[nk*4+2] = bb.z; out[nk*4+3] = bb.w;
        out[400 + nk] = (float)slab[i];
        out[500 + nk] = sscore[i];
      }
      const unsigned long long* mrow = mask + (size_t)i * NW;
      if (lane < nw) live0 &= ~mrow[lane];
      if (64 + lane < nw) live1 &= ~mrow[64 + lane];
      nk++;
      wv = bcast_live(live0, live1, w) & vmask;
      wv &= (b == 63) ? 0ULL : ~((2ULL << b) - 1ULL);  // only bits > b
    }
  }
  for (int r = nk + lane; r < 100; r += 64) {
    out[r*4+0] = 0.0f; out[r*4+1] = 0.0f; out[r*4+2] = 0.0f; out[r*4+3] = 0.0f;
    out[400 + r] = -1.0f;
    out[500 + r] = 0.0f;
  }
}

// ---------------- launch ----------------
extern "C" void kernel_launch(void* const* d_in, const int* in_sizes, int n_in,
                              void* d_out, int out_size, void* d_ws, size_t ws_size,
                              hipStream_t stream) {
  const float* feat   = (const float*)d_in[1];
  const float* props  = (const float*)d_in[2];
  const float* fc6_w  = (const float*)d_in[3];
  const float* fc6_b  = (const float*)d_in[4];
  const float* fc7_w  = (const float*)d_in[5];
  const float* fc7_b  = (const float*)d_in[6];
  const float* cls_w  = (const float*)d_in[7];
  const float* cls_b  = (const float*)d_in[8];
  const float* reg_w  = (const float*)d_in[9];
  const float* reg_b  = (const float*)d_in[10];

  char* ws = (char*)d_ws;
  size_t off = 0;
  auto alloc = [&](size_t bytes) -> void* {
    void* p = ws + off;
    off += (bytes + 255) & ~(size_t)255;
    return p;
  };

  _Float16* Xhi  = (_Float16*)alloc((size_t)P_N * FIN * 2);
  _Float16* Xlo  = (_Float16*)alloc((size_t)P_N * FIN * 2);
  float*    Pt   = (float*)alloc((size_t)KS6 * P_N * D_N * 4);   // 51.6 MB
  _Float16* h6hi = (_Float16*)alloc((size_t)P_N * D_N * 2);
  _Float16* h6lo = (_Float16*)alloc((size_t)P_N * D_N * 2);
  _Float16* h7hi = (_Float16*)alloc((size_t)P_N * D_N * 2);
  _Float16* h7lo = (_Float16*)alloc((size_t)P_N * D_N * 2);
  float*    Wpad = (float*)alloc((size_t)NHEAD * D_N * 4);
  float*    bpad = (float*)alloc((size_t)NHEAD * 4);
  float*  logits = (float*)alloc((size_t)P_N * NHEAD * 4);
  float*  cboxes = (float*)alloc((size_t)NCAND * 4 * 4);
  unsigned long long* ckeys = (unsigned long long*)alloc((size_t)NCAND * 8);
  float4*   sbox = (float4*)alloc((size_t)NCAND * 16);
  float*  sscore = (float*)alloc((size_t)NCAND * 4);
  int*      slab = (int*)alloc((size_t)NCAND * 4);
  unsigned long long* supmask = (unsigned long long*)alloc((size_t)NCAND * NW * 8); // 4.6 MB
  int*    vcount = (int*)alloc(256);
  // ft (6.9 MB) aliases Pt (51.6 MB): Pt first written after roi_align consumed ft.
  float* ft = Pt;
  (void)ws_size; (void)in_sizes; (void)n_in; (void)out_size;

  // 0) pad head weights/bias; zero vcount
  prep_head<<<NHEAD, 256, 0, stream>>>(cls_w, cls_b, reg_w, reg_b, Wpad, bpad, vcount);
  // 1) feat (C,HW) -> (HW,C)
  transpose_feat<<<dim3((HW_F + 31) / 32, C_N / 32), dim3(32, 8), 0, stream>>>(feat, ft);
  // 2) ROI align -> X hi/lo f16 (x A_SCALE)
  roi_align_k<<<dim3(P_N, 2), 256, 0, stream>>>(ft, props, Xhi, Xlo);
  // 3) fc6
  gemm_f16_3p<<<dim3(3, 8, KS6), 256, 0, stream>>>(Xhi, Xlo, fc6_w, Pt, P_N, FIN, STEPS6_PER_Z, D_N);
  reduce_bias<<<(P_N * D_N + 255) / 256, 256, 0, stream>>>(
      Pt, fc6_b, nullptr, h6hi, h6lo, P_N * D_N, KS6, D_N - 1, 1);
  // 4) fc7
  gemm_f16_3p<<<dim3(3, 8, KS7), 256, 0, stream>>>(h6hi, h6lo, fc7_w, Pt, P_N, D_N, STEPS7_PER_Z, D_N);
  reduce_bias<<<(P_N * D_N + 255) / 256, 256, 0, stream>>>(
      Pt, fc7_b, nullptr, h7hi, h7lo, P_N * D_N, KS7, D_N - 1, 1);
  // 5) head GEMM (N=128 padded) + logits reduce (no relu)
  gemm_f16_3p<<<dim3(3, 1, KSH), 256, 0, stream>>>(h7hi, h7lo, Wpad, Pt, P_N, D_N, STEPSH_PER_Z, NHEAD);
  reduce_bias<<<(P_N * NHEAD + 255) / 256, 256, 0, stream>>>(
      Pt, bpad, logits, nullptr, nullptr, P_N * NHEAD, KSH, NHEAD - 1, 0);
  // 6) softmax + decode + validity + compact (fused)
  decode_kernel<<<P_N, 64, 0, stream>>>(logits, props, cboxes, ckeys, vcount);
  // 7) sort -> gather
  sort_gather<<<1, 1024, 0, stream>>>(ckeys, vcount, cboxes, sbox, sscore, slab);
  // 8) suppression matrix (parallel) + single-wave NMS bit-scan
  iou_matrix<<<(NCAND + 3) / 4, 256, 0, stream>>>(sbox, slab, vcount, supmask);
  nms_scan<<<1, 64, 0, stream>>>(sbox, sscore, slab, vcount, supmask, (float*)d_out);
}